// Round 2
// baseline (272.800 us; speedup 1.0000x reference)
//
#include <hip/hip_runtime.h>
#include <hip/hip_fp16.h>

#define HH 256
#define WW 256
#define KK 81
#define PLANE (HH * WW)
#define SLACK 10          // tile halo: rows [ho-10, ho+10], cols [xb, xb+83]
#define TR 21             // tile rows
#define TC 84             // tile cols (64-px strip + 4+SLACK halo each side)
#define TAB (TR * TC)     // 1764 cells per plane

// Pack [B,3,H,W] fp32 -> [B,H,W] ushort4 of fp16 (c0,c1,c2,0): one 8 B cell
// carries all 3 color groups for a pixel.
__global__ __launch_bounds__(256) void pack_kernel(const float* __restrict__ in,
                                                   ushort4* __restrict__ img) {
    int idx = blockIdx.x * 256 + threadIdx.x;  // b*PLANE + pix
    int b = idx >> 16;
    int pix = idx & 0xFFFF;
    const float* base = in + (size_t)b * 3 * PLANE + pix;
    _Float16 h0 = (_Float16)base[0];
    _Float16 h1 = (_Float16)base[PLANE];
    _Float16 h2 = (_Float16)base[2 * PLANE];
    ushort4 u;
    u.x = __builtin_bit_cast(unsigned short, h0);
    u.y = __builtin_bit_cast(unsigned short, h1);
    u.z = __builtin_bit_cast(unsigned short, h2);
    u.w = 0;
    img[idx] = u;
}

__device__ __forceinline__ void acc3(float w, unsigned int pa, unsigned int pb,
                                     float& ax, float& ay, float& az) {
    __half2 ha = __builtin_bit_cast(__half2, pa);
    __half2 hb = __builtin_bit_cast(__half2, pb);
    ax = fmaf(w, __low2float(ha), ax);   // v_fma_mix_f32 (lo)
    ay = fmaf(w, __high2float(ha), ay);  // v_fma_mix_f32 (hi)
    az = fmaf(w, __low2float(hb), az);
}

// Block = 64-pixel strip of one output row. 4 waves each own 21 tap slots:
// wave w covers taps [20w, 20w+20]; the overlap slot (j==0, w>0) is
// weight-zeroed so each of the 81 taps contributes exactly once.
//
// LATENCY STRATEGY (round 2): all 63 offset/mask values (dy,dx,m x 21) are
// prefetched into statically-indexed register arrays in one fully-unrolled
// burst BEFORE __syncthreads(). The ~800-cycle LLC/HBM latency of these
// streaming (L2-miss) loads is paid ONCE per block, overlapped with tile
// staging + barrier, instead of once per unroll-4 group (which left ~840
// cycles/tap exposed at VGPR_Count=20). Compute loop then runs from regs.
//
// Input tile staged ZERO-PADDED in LDS as ONE 8 B cell per pixel
// (uint2: lo = fp16x2 c0c1, hi = fp16 c2); 4 bilinear corners are 2x
// ds_read2_b64. Tile row r == image row yb+r exactly (zeros outside the
// image) so unclamped index math is correct (DCNv2 semantics).
__global__ __launch_bounds__(256, 4) void dcn_kernel(
    const ushort4* __restrict__ img,
    const float* __restrict__ offset,
    const float* __restrict__ mask,
    const float* __restrict__ weight,
    const float* __restrict__ bias,
    float* __restrict__ out) {
    __shared__ uint2 tile[TAB];       // 14112 B interleaved cells
    __shared__ float red[3][4][64];   // 3072 B
    __shared__ float wk[KK];

    const int t = threadIdx.x;
    if (t < KK) wk[t] = weight[t];

    const int b = blockIdx.y;
    const int pix0 = blockIdx.x * 64;
    const int ho = pix0 >> 8;                 // strip stays in one output row
    const int xb = (pix0 & 255) - SLACK;
    const int yb = ho - SLACK;
    const ushort4* ib = img + (size_t)b * PLANE;

    // ---- stage tile first (these loads are L1/L2-hot, return quickly) ----
    for (int i = 0; i < 7; ++i) {
        int cid = t + i * 256;
        if (cid < TAB) {
            int r = cid / TC;
            int c = cid - r * TC;
            int iy = yb + r;
            int ix = xb + c;
            unsigned int pa = 0, pb = 0;
            if (((unsigned)iy < (unsigned)HH) & ((unsigned)ix < (unsigned)WW)) {
                ushort4 u = ib[iy * WW + ix];
                pa = (unsigned int)u.x | ((unsigned int)u.y << 16);
                pb = (unsigned int)u.z;
            }
            tile[cid] = make_uint2(pa, pb);
        }
    }

    const int w = t >> 6;
    const int lane = t & 63;
    const int pix = pix0 + lane;
    const int kbeg = w * 20;                  // 21 slots: taps [kbeg, kbeg+20]

    // ---- issue all 63 offset/mask loads (independent, stay in flight
    //      through the barrier's vmcnt drain: one latency hit per block) ----
    const float* op = offset + (size_t)b * 2 * KK * PLANE + (size_t)(2 * kbeg) * PLANE + pix;
    const float* mp = mask + (size_t)b * KK * PLANE + (size_t)kbeg * PLANE + pix;
    float pdy[21], pdx[21], pm[21];
#pragma unroll
    for (int j = 0; j < 21; ++j) {
        pdy[j] = op[(size_t)(2 * j) * PLANE];
        pdx[j] = op[(size_t)(2 * j + 1) * PLANE];
        pm[j] = mp[(size_t)j * PLANE];
    }

    __syncthreads();

    const float wof = (float)((pix0 & 255) + lane);
    float ax = 0.f, ay = 0.f, az = 0.f;
    int ky = 2 * w;                           // kbeg = 20w -> ky = 2w, kx = 2w
    int kx = 2 * w;

#pragma unroll
    for (int j = 0; j < 21; ++j) {
        const int k = kbeg + j;               // kbeg uniform per wave
        float dy = pdy[j];
        float dx = pdx[j];
        float m = pm[j] * wk[k];
        if (j == 0 && w != 0) m = 0.f;        // overlap slot contributes 0

        float py = (float)(ho - 4 + ky) + dy;
        float px = wof + ((float)(kx - 4) + dx);
        float y0f = floorf(py), x0f = floorf(px);
        float wy = py - y0f, wx = px - x0f;
        int y0 = (int)y0f, x0 = (int)x0f;

        // unclamped tile coords: tile row r == image row yb+r (zero-padded)
        int r0 = y0 - yb;
        int c0 = x0 - xb;
        bool ok = ((unsigned)r0 < (TR - 1)) & ((unsigned)c0 < (TC - 1));

        float w1y = wy * m, w0y = m - w1y;    // a0*m, a1*m (validity via data)
        float w00 = w0y * (1.f - wx), w01 = w0y * wx;
        float w10 = w1y * (1.f - wx), w11 = w1y * wx;

        uint2 q00, q01, q10, q11;
        if (__builtin_expect(__all(ok), 1)) {
            const uint2* p = &tile[r0 * TC + c0];
            q00 = p[0];
            q01 = p[1];
            q10 = p[TC];
            q11 = p[TC + 1];
        } else {
            if (ok) {
                const uint2* p = &tile[r0 * TC + c0];
                q00 = p[0];
                q01 = p[1];
                q10 = p[TC];
                q11 = p[TC + 1];
            } else {
                // fully clamped + validity-masked global fallback
                int y1 = y0 + 1, x1 = x0 + 1;
                float va0 = ((unsigned)y0 < (unsigned)HH) ? 1.f : 0.f;
                float va1 = ((unsigned)y1 < (unsigned)HH) ? 1.f : 0.f;
                float vb0 = ((unsigned)x0 < (unsigned)WW) ? 1.f : 0.f;
                float vb1 = ((unsigned)x1 < (unsigned)WW) ? 1.f : 0.f;
                w00 *= va0 * vb0;
                w01 *= va0 * vb1;
                w10 *= va1 * vb0;
                w11 *= va1 * vb1;
                int y0c = min(max(y0, 0), HH - 1);
                int y1c = min(max(y1, 0), HH - 1);
                int x0c = min(max(x0, 0), WW - 1);
                int x1c = min(max(x1, 0), WW - 1);
                ushort4 g00 = ib[y0c * WW + x0c];
                ushort4 g01 = ib[y0c * WW + x1c];
                ushort4 g10 = ib[y1c * WW + x0c];
                ushort4 g11 = ib[y1c * WW + x1c];
                q00 = make_uint2((unsigned int)g00.x | ((unsigned int)g00.y << 16), g00.z);
                q01 = make_uint2((unsigned int)g01.x | ((unsigned int)g01.y << 16), g01.z);
                q10 = make_uint2((unsigned int)g10.x | ((unsigned int)g10.y << 16), g10.z);
                q11 = make_uint2((unsigned int)g11.x | ((unsigned int)g11.y << 16), g11.z);
            }
        }

        acc3(w00, q00.x, q00.y, ax, ay, az);
        acc3(w01, q01.x, q01.y, ax, ay, az);
        acc3(w10, q10.x, q10.y, ax, ay, az);
        acc3(w11, q11.x, q11.y, ax, ay, az);

        if (++kx == 9) {
            kx = 0;
            ++ky;
        }
    }

    red[0][w][lane] = ax;
    red[1][w][lane] = ay;
    red[2][w][lane] = az;
    __syncthreads();

    if (t < 192) {
        const int c = t >> 6;
        const int l = t & 63;
        float s = red[c][0][l] + red[c][1][l] + red[c][2][l] + red[c][3][l] + bias[0];
        out[(size_t)b * 3 * PLANE + (size_t)c * PLANE + pix0 + l] = s;
    }
}

extern "C" void kernel_launch(void* const* d_in, const int* in_sizes, int n_in,
                              void* d_out, int out_size, void* d_ws, size_t ws_size,
                              hipStream_t stream) {
    const float* input = (const float*)d_in[0];
    const float* offset = (const float*)d_in[1];
    const float* mask = (const float*)d_in[2];
    const float* weight = (const float*)d_in[3];
    const float* bias = (const float*)d_in[4];
    float* out = (float*)d_out;

    const int B = in_sizes[0] / (3 * PLANE);  // 2
    ushort4* img = (ushort4*)d_ws;            // 1 MB packed fp16 image

    pack_kernel<<<B * PLANE / 256, 256, 0, stream>>>(input, img);
    dim3 grid(PLANE / 64, B);
    dcn_kernel<<<grid, 256, 0, stream>>>(img, offset, mask, weight, bias, out);
}

// Round 3
// 180.790 us; speedup vs baseline: 1.5089x; 1.5089x over previous
//
#include <hip/hip_runtime.h>
#include <hip/hip_fp16.h>

#define HH 256
#define WW 256
#define KK 81
#define PLANE (HH * WW)
#define SLACK 10          // tile halo: rows [ho-10, ho+10], cols [xb, xb+83]
#define TR 21             // tile rows
#define TC 84             // tile cols (64-px strip + 4+SLACK halo each side)
#define TAB (TR * TC)     // 1764 cells per plane

// Pack [B,3,H,W] fp32 -> [B,H,W] ushort4 of fp16 (c0,c1,c2,0): one 8 B cell
// carries all 3 color groups for a pixel.
__global__ __launch_bounds__(256) void pack_kernel(const float* __restrict__ in,
                                                   ushort4* __restrict__ img) {
    int idx = blockIdx.x * 256 + threadIdx.x;  // b*PLANE + pix
    int b = idx >> 16;
    int pix = idx & 0xFFFF;
    const float* base = in + (size_t)b * 3 * PLANE + pix;
    _Float16 h0 = (_Float16)base[0];
    _Float16 h1 = (_Float16)base[PLANE];
    _Float16 h2 = (_Float16)base[2 * PLANE];
    ushort4 u;
    u.x = __builtin_bit_cast(unsigned short, h0);
    u.y = __builtin_bit_cast(unsigned short, h1);
    u.z = __builtin_bit_cast(unsigned short, h2);
    u.w = 0;
    img[idx] = u;
}

__device__ __forceinline__ void acc3(float w, unsigned int pa, unsigned int pb,
                                     float& ax, float& ay, float& az) {
    __half2 ha = __builtin_bit_cast(__half2, pa);
    __half2 hb = __builtin_bit_cast(__half2, pb);
    ax = fmaf(w, __low2float(ha), ax);   // v_fma_mix_f32 (lo)
    ay = fmaf(w, __high2float(ha), ay);  // v_fma_mix_f32 (hi)
    az = fmaf(w, __low2float(hb), az);
}

// Block = 64-pixel strip of one output row. 4 waves each own 21 tap slots
// (wave w: taps [20w, 20w+20]; overlap slot j==0,w>0 is weight-zeroed).
//
// LATENCY STRATEGY (round 3): burst-issue all 63 offset/mask loads into
// REGISTER arrays before tile staging + barrier -> one latency hit per
// block. Round 2 failed because the consume loop held a convergent __all()
// plus a huge divergent fallback, so the unroller/SROA left the arrays in
// scratch (VGPR=64, 272 MB scratch traffic). Now:
//   pass 1: fully-unrolled, BRANCHLESS, convergence-free. Out-of-tile taps
//           get m=0 (cndmask) + clamped LDS index (always safe); a per-lane
//           bitmask records the ~never (|off|>6) escapes.
//   pass 2: rolled rare loop, re-reads dy/dx/m from GLOBAL (no register
//           array indexing), full clamped+masked gather from the image.
// wk[] LDS removed: weight folded into pm[] at prefetch via wave-uniform
// s_load of weight[kbeg+j].
//
// Input tile staged ZERO-PADDED in LDS as ONE 8 B cell per pixel
// (uint2: lo = fp16x2 c0c1, hi = fp16 c2); 4 bilinear corners = 2x
// ds_read2_b64. Tile row r == image row yb+r exactly (zeros outside the
// image) so unclamped index math is correct (DCNv2 semantics).
__global__ __launch_bounds__(256, 4) void dcn_kernel(
    const ushort4* __restrict__ img,
    const float* __restrict__ offset,
    const float* __restrict__ mask,
    const float* __restrict__ weight,
    const float* __restrict__ bias,
    float* __restrict__ out) {
    __shared__ uint2 tile[TAB];       // 14112 B interleaved cells
    __shared__ float red[3][4][64];   // 3072 B

    const int t = threadIdx.x;
    const int b = blockIdx.y;
    const int pix0 = blockIdx.x * 64;
    const int ho = pix0 >> 8;                 // strip stays in one output row
    const int xb = (pix0 & 255) - SLACK;
    const int yb = ho - SLACK;
    const ushort4* ib = img + (size_t)b * PLANE;

    const int w = t >> 6;
    const int lane = t & 63;
    const int pix = pix0 + lane;
    const int kbeg = w * 20;                  // 21 slots: taps [kbeg, kbeg+20]

    const float* op = offset + (size_t)b * 2 * KK * PLANE + (size_t)(2 * kbeg) * PLANE + pix;
    const float* mp = mask + (size_t)b * KK * PLANE + (size_t)kbeg * PLANE + pix;

    // ---- burst-issue all 63 streaming loads FIRST (oldest in vmem queue;
    //      they drain under tile staging + barrier) ----
    float pdy[21], pdx[21], pm[21];
#pragma unroll
    for (int j = 0; j < 21; ++j) {
        pdy[j] = op[(size_t)(2 * j) * PLANE];
        pdx[j] = op[(size_t)(2 * j + 1) * PLANE];
        pm[j] = mp[(size_t)j * PLANE] * weight[kbeg + j];  // wave-uniform s_load
    }

    // ---- stage tile: 1764 cells, zero outside the image ----
    for (int i = 0; i < 7; ++i) {
        int cid = t + i * 256;
        if (cid < TAB) {
            int r = cid / TC;
            int c = cid - r * TC;
            int iy = yb + r;
            int ix = xb + c;
            unsigned int pa = 0, pb = 0;
            if (((unsigned)iy < (unsigned)HH) & ((unsigned)ix < (unsigned)WW)) {
                ushort4 u = ib[iy * WW + ix];
                pa = (unsigned int)u.x | ((unsigned int)u.y << 16);
                pb = (unsigned int)u.z;
            }
            tile[cid] = make_uint2(pa, pb);
        }
    }

    __syncthreads();

    const float wof = (float)((pix0 & 255) + lane);
    float ax = 0.f, ay = 0.f, az = 0.f;
    unsigned int fail = 0u;
    int ky = 2 * w;                           // kbeg = 20w -> ky = 2w, kx = 2w
    int kx = 2 * w;

    // ---- pass 1: branchless, convergence-free, fully unrolled ----
#pragma unroll
    for (int j = 0; j < 21; ++j) {
        float m = pm[j];
        if (w != 0 && j == 0) m = 0.f;        // overlap slot contributes 0

        float py = (float)(ho - 4 + ky) + pdy[j];
        float px = wof + ((float)(kx - 4) + pdx[j]);
        float y0f = floorf(py), x0f = floorf(px);
        float wy = py - y0f, wx = px - x0f;
        int r0 = (int)y0f - yb;               // tile row (zero-padded image)
        int c0 = (int)x0f - xb;

        bool ok = ((unsigned)r0 < (TR - 1)) & ((unsigned)c0 < (TC - 1));
        fail |= (ok ? 0u : 1u) << j;
        m = ok ? m : 0.f;                     // cndmask, no branch

        float w1y = wy * m, w0y = m - w1y;    // validity via zero-padded data
        float w00 = w0y * (1.f - wx), w01 = w0y * wx;
        float w10 = w1y * (1.f - wx), w11 = w1y * wx;

        int r0c = min(max(r0, 0), TR - 2);    // clamped: LDS read always safe
        int c0c = min(max(c0, 0), TC - 2);
        const uint2* p = &tile[r0c * TC + c0c];
        uint2 q00 = p[0];
        uint2 q01 = p[1];
        uint2 q10 = p[TC];
        uint2 q11 = p[TC + 1];

        acc3(w00, q00.x, q00.y, ax, ay, az);
        acc3(w01, q01.x, q01.y, ax, ay, az);
        acc3(w10, q10.x, q10.y, ax, ay, az);
        acc3(w11, q11.x, q11.y, ax, ay, az);

        if (++kx == 9) {
            kx = 0;
            ++ky;
        }
    }

    // ---- pass 2: rare escapes (|offset| > ~6), exact global gather ----
    if (__builtin_expect(fail != 0u, 0)) {
        while (fail) {
            int j = __ffs(fail) - 1;
            fail &= fail - 1;
            if (w != 0 && j == 0) continue;   // overlap slot owned by prev wave
            int k = kbeg + j;
            float dy = op[(size_t)(2 * j) * PLANE];
            float dx = op[(size_t)(2 * j + 1) * PLANE];
            float m = mp[(size_t)j * PLANE] * weight[k];
            int kyy = k / 9;
            int kxx = k - kyy * 9;
            float py = (float)(ho - 4 + kyy) + dy;
            float px = wof + ((float)(kxx - 4) + dx);
            float y0f = floorf(py), x0f = floorf(px);
            float wy = py - y0f, wx = px - x0f;
            int y0 = (int)y0f, x0 = (int)x0f;
            int y1 = y0 + 1, x1 = x0 + 1;
            float va0 = ((unsigned)y0 < (unsigned)HH) ? 1.f : 0.f;
            float va1 = ((unsigned)y1 < (unsigned)HH) ? 1.f : 0.f;
            float vb0 = ((unsigned)x0 < (unsigned)WW) ? 1.f : 0.f;
            float vb1 = ((unsigned)x1 < (unsigned)WW) ? 1.f : 0.f;
            float w1y = wy * m, w0y = m - w1y;
            float w00 = w0y * (1.f - wx) * va0 * vb0;
            float w01 = w0y * wx * va0 * vb1;
            float w10 = w1y * (1.f - wx) * va1 * vb0;
            float w11 = w1y * wx * va1 * vb1;
            int y0c = min(max(y0, 0), HH - 1);
            int y1c = min(max(y1, 0), HH - 1);
            int x0c = min(max(x0, 0), WW - 1);
            int x1c = min(max(x1, 0), WW - 1);
            ushort4 g00 = ib[y0c * WW + x0c];
            ushort4 g01 = ib[y0c * WW + x1c];
            ushort4 g10 = ib[y1c * WW + x0c];
            ushort4 g11 = ib[y1c * WW + x1c];
            acc3(w00, (unsigned int)g00.x | ((unsigned int)g00.y << 16), g00.z, ax, ay, az);
            acc3(w01, (unsigned int)g01.x | ((unsigned int)g01.y << 16), g01.z, ax, ay, az);
            acc3(w10, (unsigned int)g10.x | ((unsigned int)g10.y << 16), g10.z, ax, ay, az);
            acc3(w11, (unsigned int)g11.x | ((unsigned int)g11.y << 16), g11.z, ax, ay, az);
        }
    }

    red[0][w][lane] = ax;
    red[1][w][lane] = ay;
    red[2][w][lane] = az;
    __syncthreads();

    if (t < 192) {
        const int c = t >> 6;
        const int l = t & 63;
        float s = red[c][0][l] + red[c][1][l] + red[c][2][l] + red[c][3][l] + bias[0];
        out[(size_t)b * 3 * PLANE + (size_t)c * PLANE + pix0 + l] = s;
    }
}

extern "C" void kernel_launch(void* const* d_in, const int* in_sizes, int n_in,
                              void* d_out, int out_size, void* d_ws, size_t ws_size,
                              hipStream_t stream) {
    const float* input = (const float*)d_in[0];
    const float* offset = (const float*)d_in[1];
    const float* mask = (const float*)d_in[2];
    const float* weight = (const float*)d_in[3];
    const float* bias = (const float*)d_in[4];
    float* out = (float*)d_out;

    const int B = in_sizes[0] / (3 * PLANE);  // 2
    ushort4* img = (ushort4*)d_ws;            // 1 MB packed fp16 image

    pack_kernel<<<B * PLANE / 256, 256, 0, stream>>>(input, img);
    dim3 grid(PLANE / 64, B);
    dcn_kernel<<<grid, 256, 0, stream>>>(img, offset, mask, weight, bias, out);
}

// Round 4
// 170.541 us; speedup vs baseline: 1.5996x; 1.0601x over previous
//
#include <hip/hip_runtime.h>
#include <hip/hip_fp16.h>

#define HH 256
#define WW 256
#define KK 81
#define PLANE (HH * WW)
#define TR 17             // tile rows: [ho-8, ho+8]
#define TC2 272           // tile cols: [-8, 263]
#define XB (-8)           // tile col origin
#define YOFF 8            // tile row origin = ho - YOFF
#define CT 4              // taps per chunk == waves per block
#define NCH 21            // ceil(81/4) chunks

// Pack [B,3,H,W] fp32 -> [B,H,W] ushort4 of fp16 (c0,c1,c2,0).
__global__ __launch_bounds__(256) void pack_kernel(const float* __restrict__ in,
                                                   ushort4* __restrict__ img) {
    int idx = blockIdx.x * 256 + threadIdx.x;  // b*PLANE + pix
    int b = idx >> 16;
    int pix = idx & 0xFFFF;
    const float* base = in + (size_t)b * 3 * PLANE + pix;
    _Float16 h0 = (_Float16)base[0];
    _Float16 h1 = (_Float16)base[PLANE];
    _Float16 h2 = (_Float16)base[2 * PLANE];
    ushort4 u;
    u.x = __builtin_bit_cast(unsigned short, h0);
    u.y = __builtin_bit_cast(unsigned short, h1);
    u.z = __builtin_bit_cast(unsigned short, h2);
    u.w = 0;
    img[idx] = u;
}

__device__ __forceinline__ void acc3(float w, unsigned int pa, unsigned int pb,
                                     float& ax, float& ay, float& az) {
    __half2 ha = __builtin_bit_cast(__half2, pa);
    __half2 hb = __builtin_bit_cast(__half2, pb);
    ax = fmaf(w, __low2float(ha), ax);   // v_fma_mix_f32 (lo)
    ay = fmaf(w, __high2float(ha), ay);  // v_fma_mix_f32 (hi)
    az = fmaf(w, __low2float(hb), az);
}

// Async stage of one 1 KB row (256 floats) into LDS: wave-uniform LDS base,
// per-lane global addr, 16 B/lane. Lines go in flight with ZERO register
// dependency -> the wave keeps executing; vmcnt drained at the barrier.
__device__ __forceinline__ void gload_lds16(const float* g, float* l) {
    __builtin_amdgcn_global_load_lds(
        (const __attribute__((address_space(1))) unsigned int*)g,
        (__attribute__((address_space(3))) unsigned int*)l,
        16, 0, 0);
}

// Block = ONE output row (256 px), 4 waves, wave w owns px [64w,64w+64),
// computing ALL 81 taps serially (no cross-wave reduction).
//
// MLP STRATEGY (round 4): offset/mask consumed as whole channel rows.
// Chunk c = taps [4c,4c+4); wave w stages tap 4c+w's 3 rows (dy,dx,m) via
// 3x global_load_lds into cbuf[c&1] (double-buffered). 2-phase pipeline:
//   issue stage(c+1) -> compute chunk c from LDS -> __syncthreads (drains
//   vmcnt+lgkmcnt). The ~700 cy stream latency hides under chunk-c compute;
//   in-flight lines/CU ~ 4 waves x 3 instr x 8 lines x 2 blocks ~ 192
//   (vs ~39 measured for the register-coupled variants).
// Bilinear corners come from the zero-padded LDS tile (lgkmcnt path --
// independent of the vmcnt staging pipeline, so they don't serialize it).
__global__ __launch_bounds__(256, 2) void dcn_kernel(
    const ushort4* __restrict__ img,
    const float* __restrict__ offset,
    const float* __restrict__ mask,
    const float* __restrict__ weight,
    const float* __restrict__ bias,
    float* __restrict__ out) {
    __shared__ uint2 tile[TR * TC2];       // 36992 B zero-padded fp16 image
    __shared__ float cbuf[2][CT][3][256];  // 24576 B offset/mask chunks

    const int t = threadIdx.x;             // == wo (output col)
    const int w = t >> 6;
    const int lane = t & 63;
    const int b = blockIdx.y;
    const int ho = blockIdx.x;
    const int yb = ho - YOFF;
    const ushort4* ib = img + (size_t)b * PLANE;

    const float* orow = offset + (size_t)b * 2 * KK * PLANE + (size_t)ho * WW;
    const float* mrow = mask + (size_t)b * KK * PLANE + (size_t)ho * WW;

    // ---- stage chunk 0 (async; drains under tile staging + barrier) ----
    {
        int k = w;                          // chunk 0, tap w
        float* dst = &cbuf[0][w][0][0];
        const float* gdy = orow + (size_t)(2 * k) * PLANE + lane * 4;
        gload_lds16(gdy, dst);
        gload_lds16(gdy + PLANE, dst + 256);
        gload_lds16(mrow + (size_t)k * PLANE + lane * 4, dst + 512);
    }

    // ---- stage zero-padded image tile (L2-hot: image is 1 MB total) ----
    for (int i = 0; i < 19; ++i) {
        int cid = t + i * 256;
        if (cid < TR * TC2) {
            int r = cid / TC2;
            int c = cid - r * TC2;
            int iy = yb + r;
            int ix = XB + c;
            unsigned int pa = 0, pb = 0;
            if (((unsigned)iy < (unsigned)HH) & ((unsigned)ix < (unsigned)WW)) {
                ushort4 u = ib[iy * WW + ix];
                pa = (unsigned int)u.x | ((unsigned int)u.y << 16);
                pb = (unsigned int)u.z;
            }
            tile[cid] = make_uint2(pa, pb);
        }
    }
    __syncthreads();                        // drains vmcnt(0): chunk 0 ready

    const float wof = (float)t;
    float ax = 0.f, ay = 0.f, az = 0.f;

    for (int c = 0; c < NCH; ++c) {
        // ---- issue next chunk's 3 async row-stages (no reg dependency) ----
        {
            int k = (c + 1) * CT + w;
            if (k < KK) {
                float* dst = &cbuf[(c + 1) & 1][w][0][0];
                const float* gdy = orow + (size_t)(2 * k) * PLANE + lane * 4;
                gload_lds16(gdy, dst);
                gload_lds16(gdy + PLANE, dst + 256);
                gload_lds16(mrow + (size_t)k * PLANE + lane * 4, dst + 512);
            }
        }

        const int cur = c & 1;
        unsigned int fl = 0;

        // ---- compute 4 taps for this wave's 64 px (branchless pass 1) ----
#pragma unroll
        for (int tc = 0; tc < CT; ++tc) {
            int k = c * CT + tc;
            if (k < KK) {                   // wave-uniform guard
                const float* cb = &cbuf[cur][tc][0][0];
                float dy = cb[t];
                float dx = cb[256 + t];
                float m = cb[512 + t] * weight[k];   // s_load, scalar-cached
                int ky = k / 9, kx = k - ky * 9;     // uniform
                float py = (float)(ho - 4 + ky) + dy;
                float px = wof + ((float)(kx - 4) + dx);
                float y0f = floorf(py), x0f = floorf(px);
                float wy = py - y0f, wx = px - x0f;
                int r0 = (int)y0f - yb;     // tile coords (zero-padded img)
                int c0 = (int)x0f - XB;

                bool ok = ((unsigned)r0 < (TR - 1)) & ((unsigned)c0 < (TC2 - 1));
                fl |= (ok ? 0u : 1u) << tc;
                m = ok ? m : 0.f;           // cndmask, no branch

                float w1y = wy * m, w0y = m - w1y;  // validity via data
                float w00 = w0y * (1.f - wx), w01 = w0y * wx;
                float w10 = w1y * (1.f - wx), w11 = w1y * wx;

                int r0c = min(max(r0, 0), TR - 2);  // LDS read always safe
                int c0c = min(max(c0, 0), TC2 - 2);
                const uint2* p = &tile[r0c * TC2 + c0c];
                uint2 q00 = p[0];
                uint2 q01 = p[1];
                uint2 q10 = p[TC2];
                uint2 q11 = p[TC2 + 1];

                acc3(w00, q00.x, q00.y, ax, ay, az);
                acc3(w01, q01.x, q01.y, ax, ay, az);
                acc3(w10, q10.x, q10.y, ax, ay, az);
                acc3(w11, q11.x, q11.y, ax, ay, az);
            }
        }

        // ---- rare escapes (|offset| beyond halo): exact masked gather ----
        if (__builtin_expect(fl != 0u, 0)) {
            while (fl) {
                int tc = __ffs(fl) - 1;
                fl &= fl - 1;
                int k = c * CT + tc;
                const float* cb = &cbuf[cur][0][0][0] + tc * 768;
                float dy = cb[t];
                float dx = cb[256 + t];
                float m = cb[512 + t] * weight[k];
                int ky = k / 9, kx = k - ky * 9;
                float py = (float)(ho - 4 + ky) + dy;
                float px = wof + ((float)(kx - 4) + dx);
                float y0f = floorf(py), x0f = floorf(px);
                float wy = py - y0f, wx = px - x0f;
                int y0 = (int)y0f, x0 = (int)x0f;
                int y1 = y0 + 1, x1 = x0 + 1;
                float va0 = ((unsigned)y0 < (unsigned)HH) ? 1.f : 0.f;
                float va1 = ((unsigned)y1 < (unsigned)HH) ? 1.f : 0.f;
                float vb0 = ((unsigned)x0 < (unsigned)WW) ? 1.f : 0.f;
                float vb1 = ((unsigned)x1 < (unsigned)WW) ? 1.f : 0.f;
                float w1y = wy * m, w0y = m - w1y;
                float w00 = w0y * (1.f - wx) * va0 * vb0;
                float w01 = w0y * wx * va0 * vb1;
                float w10 = w1y * (1.f - wx) * va1 * vb0;
                float w11 = w1y * wx * va1 * vb1;
                int y0c = min(max(y0, 0), HH - 1);
                int y1c = min(max(y1, 0), HH - 1);
                int x0c = min(max(x0, 0), WW - 1);
                int x1c = min(max(x1, 0), WW - 1);
                ushort4 g00 = ib[y0c * WW + x0c];
                ushort4 g01 = ib[y0c * WW + x1c];
                ushort4 g10 = ib[y1c * WW + x0c];
                ushort4 g11 = ib[y1c * WW + x1c];
                acc3(w00, (unsigned int)g00.x | ((unsigned int)g00.y << 16), g00.z, ax, ay, az);
                acc3(w01, (unsigned int)g01.x | ((unsigned int)g01.y << 16), g01.z, ax, ay, az);
                acc3(w10, (unsigned int)g10.x | ((unsigned int)g10.y << 16), g10.z, ax, ay, az);
                acc3(w11, (unsigned int)g11.x | ((unsigned int)g11.y << 16), g11.z, ax, ay, az);
            }
        }

        __syncthreads();   // drains vmcnt (next chunk ready) + protects cbuf
    }

    // ---- direct write-out: no reduction needed ----
    float bs = bias[0];
    float* ob = out + (size_t)b * 3 * PLANE + (size_t)ho * WW + t;
    ob[0] = ax + bs;
    ob[PLANE] = ay + bs;
    ob[2 * PLANE] = az + bs;
}

extern "C" void kernel_launch(void* const* d_in, const int* in_sizes, int n_in,
                              void* d_out, int out_size, void* d_ws, size_t ws_size,
                              hipStream_t stream) {
    const float* input = (const float*)d_in[0];
    const float* offset = (const float*)d_in[1];
    const float* mask = (const float*)d_in[2];
    const float* weight = (const float*)d_in[3];
    const float* bias = (const float*)d_in[4];
    float* out = (float*)d_out;

    const int B = in_sizes[0] / (3 * PLANE);  // 2
    ushort4* img = (ushort4*)d_ws;            // 1 MB packed fp16 image

    pack_kernel<<<B * PLANE / 256, 256, 0, stream>>>(input, img);
    dim3 grid(HH, B);                         // one block per output row
    dcn_kernel<<<grid, 256, 0, stream>>>(img, offset, mask, weight, bias, out);
}